// Round 10
// baseline (398.154 us; speedup 1.0000x reference)
//
#include <hip/hip_runtime.h>
#include <hip/hip_bf16.h>
#include <math.h>

// GATv2 GNN: 3 layers, HIDDEN=128, HEADS=4, HEAD_DIM=32, + residual/ELU/LN, mean-pool.
//  - R21 (4th submit; R7/R8 GPU-acquisition timeouts, R9 container failure —
//    all infra, kernel never measured):
//    dense 3-stage CSR build replaces padded-bucket tmp round-trip.
//      K1 = count (deg atomics, 800K/50K addrs) U prep_wfrag
//      K2 = per-bucket scan (offsets/cur; trivial, hides) U emb+dual0
//      K3 = scatter (cur atomics -> srt direct; no tmp)
//    Kills: 6.4MB tmp write+read, bin's LDS double-histogram, bucket's
//    17-barrier scan kernel. Keeps padded-bucket offsets layout (no global
//    scan; gat_layer untouched). Edge-order nondeterminism already present
//    (absmax bit-stable 2^-11 across runs -> numerics are order-insensitive).
//    OOB audit: srt pos < bucket_base + 4096 (deg sum/bucket: mean 2046,
//    sigma~45 -> 40+ sigma headroom); scan overlay 512B of 34KB LDS.
//  - R20 lesson: bin@1024 REGRESSED +14us — same-address global atomic RMWs
//    serialize at the owning L2 slice (~900 hits/addr x ~20ns). Contended-addr
//    count is the cost, not total atomics. (deg/cur: 16/addr -> safe.)
//  - R19 lesson: per-block device-scope fences -> per-fence XCD-L2 writebacks,
//    87us. Last-block-done patterns are fabric-serialized on 8 XCDs.
//  - R18: fuse emb->dual0 + grid-stitch = -9.7us; in-LDS A-path bit-safe.
//  - gat_layer pinned ~48.3us: random-gather service equilibrium. DO NOT TOUCH.
//  - R12: DPP row ops illegal on gfx950. h = fp16 hi/lo pair (R14).

#define HID 128
#define BKT_SHIFT 7                 // 128 dsts per scan bucket
#define BKT_DSTS (1 << BKT_SHIFT)
#define CAP_SHIFT 12                // 4096 edge slots per bucket (avg ~2046)
#define CNT_BLOCKS 1024
#define SCT_BLOCKS 1024

typedef __attribute__((ext_vector_type(8))) short bf8_t;
typedef __attribute__((ext_vector_type(8))) _Float16 hf8_t;
typedef __attribute__((ext_vector_type(2))) _Float16 h2_t;
typedef __attribute__((ext_vector_type(4))) float f4_t;

__device__ __forceinline__ unsigned short f2bf(float f) {
    unsigned u = __float_as_uint(f);
    u += 0x7fff + ((u >> 16) & 1);          // RTNE
    return (unsigned short)(u >> 16);
}
__device__ __forceinline__ float bf2f(unsigned short h) {
    return __uint_as_float(((unsigned)h) << 16);
}
__device__ __forceinline__ unsigned short f2h(float f) {
    _Float16 h = (_Float16)f;               // RTNE
    return __builtin_bit_cast(unsigned short, h);
}
__device__ __forceinline__ float h2f(unsigned short u) {
    return (float)__builtin_bit_cast(_Float16, u);
}
__device__ __forceinline__ h2_t shfl_xor_h2(h2_t v, int m) {
    return __builtin_bit_cast(h2_t, __shfl_xor(__builtin_bit_cast(int, v), m, 64));
}

// ---------------- K1: count (blocks 0..CNT-1) U prep_wfrag (CNT..CNT+447) ----

__global__ __launch_bounds__(256) void k1_count_prep(
    const int* __restrict__ ei, int* __restrict__ deg, int E,
    const float* __restrict__ embW, const float* __restrict__ linlW,
    const float* __restrict__ linrW, unsigned short* __restrict__ frag) {
    int tid = threadIdx.x;

    if (blockIdx.x < CNT_BLOCKS) {
        // ----- degree count: 800K atomics over 50K addresses (16/addr) -----
        int stride = CNT_BLOCKS * 256;
        for (int e = blockIdx.x * 256 + tid; e < E; e += stride)
            atomicAdd(&deg[ei[E + e]], 1);
    } else {
        // ----- prep_wfrag: slot0 emb bf16 hi|lo; slots 1..6 fp16 single -----
        int bid = blockIdx.x - CNT_BLOCKS;    // 0..447
        int w = bid >> 6;                     // 0..6
        const float* W;
        if (w == 0)      W = embW;
        else if (w <= 3) W = linlW + (size_t)(w - 1) * 16384;
        else             W = linrW + (size_t)(w - 4) * 16384;

        int i = ((bid & 63) << 8) + tid;      // 0..16383
        int j = i & 7;
        int lane = (i >> 3) & 63;
        int t = i >> 9;                       // kk*8+nn
        int kk = t >> 3, nn = t & 7;
        int k = kk * 32 + (lane >> 4) * 8 + j;
        int n = nn * 16 + (lane & 15);
        float v = W[k * 128 + n];
        if (w == 0) {
            unsigned short hi = f2bf(v);
            frag[i] = hi;
            frag[16384 + i] = f2bf(v - bf2f(hi));
        } else {
            int slot = (w <= 3) ? (1 + 2 * (w - 1)) : (2 + 2 * (w - 4));
            frag[32768 + (size_t)(slot - 1) * 16384 + i] = f2h(v);
        }
    }
}

// ---------------- K2: fused emb->dual0 (blocks 0..GBLK-1) U scan --------------
// scan: per-bucket 128-wide exclusive scan of deg -> offsets/cur in padded
// layout (bkt<<CAP_SHIFT + excl). Trivial (~2us for 391 blocks) -> hides
// completely under the 782 GEMM blocks.

__global__ __launch_bounds__(256) void k2_scan_embdual(
    const int* __restrict__ deg, int* __restrict__ offsets, int* __restrict__ cur,
    int N, int GBLK,
    const float* __restrict__ Afp, const unsigned short* __restrict__ wfrag,
    const float* __restrict__ emb_b,
    const float* __restrict__ bl0, const float* __restrict__ br0,
    unsigned short* __restrict__ Chi, unsigned short* __restrict__ Clo,
    unsigned short* __restrict__ xl, unsigned short* __restrict__ xr) {
    __shared__ __align__(16) unsigned short As[2][64][136];
    int tid = threadIdx.x;

    if (blockIdx.x >= GBLK) {
        // ----- per-bucket scan (overlay sc on As) -----
        int* sc = (int*)As;
        int b = blockIdx.x - GBLK;
        int d = (b << BKT_SHIFT) + tid;       // tid<128 active
        int v = 0;
        if (tid < BKT_DSTS) {
            v = (d < N) ? deg[d] : 0;
            sc[tid] = v;
        }
        __syncthreads();
        for (int off = 1; off < BKT_DSTS; off <<= 1) {
            int u = (tid < BKT_DSTS && tid >= off) ? sc[tid - off] : 0;
            __syncthreads();
            if (tid < BKT_DSTS) sc[tid] += u;
            __syncthreads();
        }
        if (tid < BKT_DSTS && d < N) {
            int o = (b << CAP_SHIFT) + sc[tid] - v;   // exclusive, absolute
            offsets[d] = o;
            cur[d] = o;
        }
        return;
    }

    // ----- fused emb + dual0 -----
    int m0 = blockIdx.x * 64;

    #pragma unroll
    for (int i = 0; i < 8; ++i) {
        int idx = tid + i * 256;
        int r = idx >> 5, c4 = idx & 31;
        int row = m0 + r;
        float4 v = make_float4(0.f, 0.f, 0.f, 0.f);
        if (row < N) v = *(const float4*)(Afp + (size_t)row * HID + c4 * 4);
        ushort4 hi, lo;
        hi.x = f2bf(v.x); lo.x = f2bf(v.x - bf2f(hi.x));
        hi.y = f2bf(v.y); lo.y = f2bf(v.y - bf2f(hi.y));
        hi.z = f2bf(v.z); lo.z = f2bf(v.z - bf2f(hi.z));
        hi.w = f2bf(v.w); lo.w = f2bf(v.w - bf2f(hi.w));
        *(ushort4*)&As[0][r][c4 * 4] = hi;
        *(ushort4*)&As[1][r][c4 * 4] = lo;
    }
    __syncthreads();

    int wave = tid >> 6, lane = tid & 63;
    int mrow = lane & 15;
    int quad = lane >> 4;

    f4_t acc[8];
    #pragma unroll
    for (int nn = 0; nn < 8; ++nn) acc[nn] = (f4_t)(0.f);

    #pragma unroll
    for (int kk = 0; kk < 4; ++kk) {
        bf8_t ah = *(const bf8_t*)&As[0][wave * 16 + mrow][kk * 32 + quad * 8];
        bf8_t al = *(const bf8_t*)&As[1][wave * 16 + mrow][kk * 32 + quad * 8];
        const unsigned short* bp = wfrag + kk * 4096 + lane * 8;
        #pragma unroll
        for (int nn = 0; nn < 8; ++nn) {
            bf8_t bh = *(const bf8_t*)(bp + nn * 512);
            bf8_t bl = *(const bf8_t*)(bp + nn * 512 + 16384);
            acc[nn] = __builtin_amdgcn_mfma_f32_16x16x32_bf16(ah, bh, acc[nn], 0, 0, 0);
            acc[nn] = __builtin_amdgcn_mfma_f32_16x16x32_bf16(ah, bl, acc[nn], 0, 0, 0);
            acc[nn] = __builtin_amdgcn_mfma_f32_16x16x32_bf16(al, bh, acc[nn], 0, 0, 0);
        }
    }

    int lrow0 = wave * 16 + quad * 4;
    __syncthreads();   // all As bf16 reads done; stage h hi->plane0, lo->plane1
    #pragma unroll
    for (int nn = 0; nn < 8; ++nn) {
        int col = nn * 16 + mrow;
        float b = emb_b[col];
        #pragma unroll
        for (int r = 0; r < 4; ++r) {
            float o = acc[nn][r] + b;
            unsigned short hh = f2h(o);
            As[0][lrow0 + r][col] = hh;
            As[1][lrow0 + r][col] = f2h(o - h2f(hh));
        }
    }
    __syncthreads();

    // store h (hi/lo) AND pull dual0 A-fragments from the same staged tile
    hf8_t afr[4];
    #pragma unroll
    for (int kk = 0; kk < 4; ++kk)
        afr[kk] = *(const hf8_t*)&As[0][wave * 16 + mrow][kk * 32 + quad * 8];
    #pragma unroll
    for (int i = 0; i < 4; ++i) {
        int idx = tid + i * 256;
        int r = idx >> 4, c8 = idx & 15;
        int row = m0 + r;
        if (row < N) {
            *(uint4*)(Chi + (size_t)row * HID + c8 * 8) = *(uint4*)&As[0][r][c8 * 8];
            *(uint4*)(Clo + (size_t)row * HID + c8 * 8) = *(uint4*)&As[1][r][c8 * 8];
        }
    }

    // dual0 GEMM on in-register fragments (B = wfrag slots 1,2)
    f4_t acc0[8], acc1[8];
    #pragma unroll
    for (int nn = 0; nn < 8; ++nn) {
        acc0[nn] = (f4_t)(0.f);
        acc1[nn] = (f4_t)(0.f);
    }
    const unsigned short* Bl = wfrag + 32768;
    const unsigned short* Br = wfrag + 49152;
    #pragma unroll
    for (int kk = 0; kk < 4; ++kk) {
        const unsigned short* bp0 = Bl + kk * 4096 + lane * 8;
        const unsigned short* bp1 = Br + kk * 4096 + lane * 8;
        #pragma unroll
        for (int nn = 0; nn < 8; ++nn) {
            hf8_t bb0 = *(const hf8_t*)(bp0 + nn * 512);
            hf8_t bb1 = *(const hf8_t*)(bp1 + nn * 512);
            acc0[nn] = __builtin_amdgcn_mfma_f32_16x16x32_f16(afr[kk], bb0, acc0[nn], 0, 0, 0);
            acc1[nn] = __builtin_amdgcn_mfma_f32_16x16x32_f16(afr[kk], bb1, acc1[nn], 0, 0, 0);
        }
    }

    __syncthreads();   // h stores + frag reads done; restage xl->0, xr->1
    #pragma unroll
    for (int nn = 0; nn < 8; ++nn) {
        int col = nn * 16 + mrow;
        float bb0 = bl0[col];
        float bb1 = br0[col];
        #pragma unroll
        for (int r = 0; r < 4; ++r) {
            As[0][lrow0 + r][col] = f2h(acc0[nn][r] + bb0);
            As[1][lrow0 + r][col] = f2h(acc1[nn][r] + bb1);
        }
    }
    __syncthreads();
    #pragma unroll
    for (int i = 0; i < 4; ++i) {
        int idx = tid + i * 256;
        int r = idx >> 4, c8 = idx & 15;
        int row = m0 + r;
        if (row < N) {
            *(uint4*)(xl + (size_t)row * HID + c8 * 8) = *(uint4*)&As[0][r][c8 * 8];
            *(uint4*)(xr + (size_t)row * HID + c8 * 8) = *(uint4*)&As[1][r][c8 * 8];
        }
    }
}

// ---------------- K3: scatter — direct srt build, no tmp ----------------

__global__ __launch_bounds__(256) void k3_scatter(const int* __restrict__ ei,
                                                  int* __restrict__ cur,
                                                  unsigned short* __restrict__ srt,
                                                  int E) {
    int stride = SCT_BLOCKS * 256;
    for (int e = blockIdx.x * 256 + threadIdx.x; e < E; e += stride) {
        int d = ei[E + e];
        int pos = atomicAdd(&cur[d], 1);      // 16 hits/addr avg — no hot spot
        srt[pos] = (unsigned short)ei[e];
    }
}

// ---------------- dual GEMM (fp16 single-pass): xl/xr = h @ Wl/Wr + b ----------

__global__ __launch_bounds__(256) void gemm_dual_f16(
    const unsigned short* __restrict__ Ah,
    const unsigned short* __restrict__ Bf0, const unsigned short* __restrict__ Bf1,
    const float* __restrict__ b0, const float* __restrict__ b1,
    unsigned short* __restrict__ C0h, unsigned short* __restrict__ C1h, int M) {
    __shared__ __align__(16) unsigned short As[2][64][136];
    int m0 = blockIdx.x * 64;
    int tid = threadIdx.x;

    #pragma unroll
    for (int i = 0; i < 4; ++i) {
        int idx = tid + i * 256;
        int r = idx >> 4, c8 = idx & 15;
        int row = m0 + r;
        uint4 v = make_uint4(0, 0, 0, 0);
        if (row < M) v = *(const uint4*)(Ah + (size_t)row * HID + c8 * 8);
        *(uint4*)&As[0][r][c8 * 8] = v;
    }
    __syncthreads();

    int wave = tid >> 6, lane = tid & 63;
    int mrow = lane & 15;
    int quad = lane >> 4;

    f4_t acc0[8], acc1[8];
    #pragma unroll
    for (int nn = 0; nn < 8; ++nn) {
        acc0[nn] = (f4_t)(0.f);
        acc1[nn] = (f4_t)(0.f);
    }

    #pragma unroll
    for (int kk = 0; kk < 4; ++kk) {
        hf8_t a = *(const hf8_t*)&As[0][wave * 16 + mrow][kk * 32 + quad * 8];
        const unsigned short* bp0 = Bf0 + kk * 4096 + lane * 8;
        const unsigned short* bp1 = Bf1 + kk * 4096 + lane * 8;
        #pragma unroll
        for (int nn = 0; nn < 8; ++nn) {
            hf8_t bb0 = *(const hf8_t*)(bp0 + nn * 512);
            hf8_t bb1 = *(const hf8_t*)(bp1 + nn * 512);
            acc0[nn] = __builtin_amdgcn_mfma_f32_16x16x32_f16(a, bb0, acc0[nn], 0, 0, 0);
            acc1[nn] = __builtin_amdgcn_mfma_f32_16x16x32_f16(a, bb1, acc1[nn], 0, 0, 0);
        }
    }

    int lrow0 = wave * 16 + quad * 4;
    __syncthreads();   // all As reads done; stage xl->plane0, xr->plane1
    #pragma unroll
    for (int nn = 0; nn < 8; ++nn) {
        int col = nn * 16 + mrow;
        float bb0 = b0[col];
        float bb1 = b1[col];
        #pragma unroll
        for (int r = 0; r < 4; ++r) {
            As[0][lrow0 + r][col] = f2h(acc0[nn][r] + bb0);
            As[1][lrow0 + r][col] = f2h(acc1[nn][r] + bb1);
        }
    }
    __syncthreads();
    #pragma unroll
    for (int i = 0; i < 4; ++i) {
        int idx = tid + i * 256;
        int r = idx >> 4, c8 = idx & 15;
        int row = m0 + r;
        if (row < M) {
            *(uint4*)(C0h + (size_t)row * HID + c8 * 8) = *(uint4*)&As[0][r][c8 * 8];
            *(uint4*)(C1h + (size_t)row * HID + c8 * 8) = *(uint4*)&As[1][r][c8 * 8];
        }
    }
}

// ---------------- GATv2 layer (unchanged — pinned at gather equilibrium) -------

__device__ __forceinline__ void edge_math(uint4 rv, const h2_t xr2[4], const h2_t av2[4],
                                          h2_t xv[4], float* pOut) {
    const h2_t slope2 = {(_Float16)0.2f, (_Float16)0.2f};
    xv[0] = __builtin_bit_cast(h2_t, rv.x); xv[1] = __builtin_bit_cast(h2_t, rv.y);
    xv[2] = __builtin_bit_cast(h2_t, rv.z); xv[3] = __builtin_bit_cast(h2_t, rv.w);
    h2_t p2 = (h2_t)((_Float16)0.f);
    #pragma unroll
    for (int i = 0; i < 4; ++i) {
        h2_t e = xv[i] + xr2[i];
        e = __builtin_elementwise_max(e, e * slope2);
        p2 = e * av2[i] + p2;
    }
    *pOut = (float)p2[0] + (float)p2[1];
}

__global__ __launch_bounds__(256) void gat_layer(
    const unsigned short* __restrict__ xlh,   // fp16 [N,128]
    const unsigned short* __restrict__ xrh,   // fp16 [N,128]
    const int* __restrict__ offsets, const int* __restrict__ deg,
    const unsigned short* __restrict__ srt,
    const float* __restrict__ att,
    const float* __restrict__ convb,
    const float* __restrict__ lng, const float* __restrict__ lnb,
    unsigned short* __restrict__ Hhi, unsigned short* __restrict__ Hlo, int N) {
    int wv = (blockIdx.x * blockDim.x + threadIdx.x) >> 6;
    int lane = threadIdx.x & 63;
    if (wv >= N) return;
    int n = wv;
    int quarter = lane >> 4;
    int f0 = (lane & 15) * 8;
    const unsigned short* xbase = xlh + f0;

    h2_t xr2[4], av2[4];
    {
        uint4 xv = *(const uint4*)(xrh + (size_t)n * HID + f0);
        xr2[0] = __builtin_bit_cast(h2_t, xv.x);
        xr2[1] = __builtin_bit_cast(h2_t, xv.y);
        xr2[2] = __builtin_bit_cast(h2_t, xv.z);
        xr2[3] = __builtin_bit_cast(h2_t, xv.w);
        float a[8];
        *(float4*)&a[0] = *(const float4*)(att + f0);
        *(float4*)&a[4] = *(const float4*)(att + f0 + 4);
        #pragma unroll
        for (int i = 0; i < 4; ++i)
            av2[i] = (h2_t){(_Float16)a[2 * i], (_Float16)a[2 * i + 1]};
    }

    float d = 0.f;
    h2_t acc2[4];
    #pragma unroll
    for (int i = 0; i < 4; ++i) acc2[i] = (h2_t)((_Float16)0.f);
    int start = offsets[n], cnt = deg[n];

    int j = 0;
    for (; j + 16 <= cnt; j += 16) {
        int s[4];
        #pragma unroll
        for (int u = 0; u < 4; ++u) s[u] = srt[start + j + 4 * u + quarter];
        uint4 rv[4];
        #pragma unroll
        for (int u = 0; u < 4; ++u)
            rv[u] = *(const uint4*)(xbase + (size_t)s[u] * HID);
        h2_t xv[4][4];
        float p[4];
        #pragma unroll
        for (int u = 0; u < 4; ++u) edge_math(rv[u], xr2, av2, xv[u], &p[u]);
        h2_t p01 = {(_Float16)p[0], (_Float16)p[1]};
        h2_t p23 = {(_Float16)p[2], (_Float16)p[3]};
        p01 += shfl_xor_h2(p01, 1); p23 += shfl_xor_h2(p23, 1);
        p01 += shfl_xor_h2(p01, 2); p23 += shfl_xor_h2(p23, 2);
        float w[4];
        w[0] = __expf((float)p01[0]); w[1] = __expf((float)p01[1]);
        w[2] = __expf((float)p23[0]); w[3] = __expf((float)p23[1]);
        #pragma unroll
        for (int u = 0; u < 4; ++u) {
            d += w[u];
            h2_t w2 = (h2_t)((_Float16)w[u]);
            #pragma unroll
            for (int i = 0; i < 4; ++i) acc2[i] = w2 * xv[u][i] + acc2[i];
        }
    }
    for (; j + 4 <= cnt; j += 4) {
        int s = srt[start + j + quarter];
        uint4 rv = *(const uint4*)(xbase + (size_t)s * HID);
        h2_t xv[4];
        float p;
        edge_math(rv, xr2, av2, xv, &p);
        p += __shfl_xor(p, 1, 64);
        p += __shfl_xor(p, 2, 64);
        float w = __expf(p);
        d += w;
        h2_t w2 = (h2_t)((_Float16)w);
        #pragma unroll
        for (int i = 0; i < 4; ++i) acc2[i] = w2 * xv[i] + acc2[i];
    }
    if (j < cnt) {
        int r = cnt - j;
        int idx = j + quarter; if (idx > cnt - 1) idx = cnt - 1;
        int s = srt[start + idx];
        uint4 rv = *(const uint4*)(xbase + (size_t)s * HID);
        h2_t xv[4];
        float p;
        edge_math(rv, xr2, av2, xv, &p);
        p += __shfl_xor(p, 1, 64);
        p += __shfl_xor(p, 2, 64);
        float w = (quarter < r) ? __expf(p) : 0.f;
        d += w;
        h2_t w2 = (h2_t)((_Float16)w);
        #pragma unroll
        for (int i = 0; i < 4; ++i) acc2[i] = w2 * xv[i] + acc2[i];
    }

    #pragma unroll
    for (int i = 0; i < 4; ++i) {
        acc2[i] += shfl_xor_h2(acc2[i], 16);
        acc2[i] += shfl_xor_h2(acc2[i], 32);
    }
    d += __shfl_xor(d, 16, 64);
    d += __shfl_xor(d, 32, 64);

    float acc[8];
    #pragma unroll
    for (int i = 0; i < 4; ++i) {
        acc[2 * i]     = (float)acc2[i][0];
        acc[2 * i + 1] = (float)acc2[i][1];
    }

    float inv = 1.f / (d + 1e-16f);
    float t[8];
    {
        float cb[8];
        *(float4*)&cb[0] = *(const float4*)(convb + f0);
        *(float4*)&cb[4] = *(const float4*)(convb + f0 + 4);
        uint4 rh = *(const uint4*)(Hhi + (size_t)n * HID + f0);
        uint4 rl = *(const uint4*)(Hlo + (size_t)n * HID + f0);
        const unsigned short* hs = (const unsigned short*)&rh;
        const unsigned short* ls = (const unsigned short*)&rl;
        #pragma unroll
        for (int i = 0; i < 8; ++i) {
            float g = acc[i] * inv + cb[i];
            g = (g > 0.f) ? g : (__expf(g) - 1.f);
            t[i] = g + (h2f(hs[i]) + h2f(ls[i]));
        }
    }

    float sum = 0.f;
    #pragma unroll
    for (int i = 0; i < 8; ++i) sum += t[i];
    #pragma unroll
    for (int m = 1; m <= 8; m <<= 1) sum += __shfl_xor(sum, m, 64);
    float mu = sum * (1.f / 128.f);
    float q[8], vs = 0.f;
    #pragma unroll
    for (int i = 0; i < 8; ++i) { q[i] = t[i] - mu; vs += q[i] * q[i]; }
    #pragma unroll
    for (int m = 1; m <= 8; m <<= 1) vs += __shfl_xor(vs, m, 64);
    float rstd = rsqrtf(vs * (1.f / 128.f) + 1e-5f);

    if (quarter == 0) {
        float gv[8], bv[8], o[8];
        *(float4*)&gv[0] = *(const float4*)(lng + f0);
        *(float4*)&gv[4] = *(const float4*)(lng + f0 + 4);
        *(float4*)&bv[0] = *(const float4*)(lnb + f0);
        *(float4*)&bv[4] = *(const float4*)(lnb + f0 + 4);
        #pragma unroll
        for (int i = 0; i < 8; ++i) o[i] = q[i] * rstd * gv[i] + bv[i];
        unsigned short hh[8], hl[8];
        #pragma unroll
        for (int i = 0; i < 8; ++i) {
            hh[i] = f2h(o[i]);
            hl[i] = f2h(o[i] - h2f(hh[i]));
        }
        *(uint4*)(Hhi + (size_t)n * HID + f0) = *(uint4*)&hh[0];
        *(uint4*)(Hlo + (size_t)n * HID + f0) = *(uint4*)&hl[0];
    }
}

// ---------------- mean pool, 2-stage (reads fp16 hi/lo h) ----------------

__global__ __launch_bounds__(256) void pool_partial(const unsigned short* __restrict__ Hhi,
                                                    const unsigned short* __restrict__ Hlo,
                                                    const int* __restrict__ batch,
                                                    float* __restrict__ sums, int N) {
    __shared__ int bsh[64];
    int c0 = blockIdx.x * 64;
    int tid = threadIdx.x;
    if (tid < 64) bsh[tid] = (c0 + tid < N) ? batch[c0 + tid] : -1;
    __syncthreads();

    int r = tid >> 5;
    int f0 = (tid & 31) * 4;
    float4 acc = make_float4(0.f, 0.f, 0.f, 0.f);
    int curg = -1;
    #pragma unroll
    for (int i = 0; i < 8; ++i) {
        int li = r * 8 + i;
        int g = bsh[li];
        if (g < 0) break;
        if (g != curg) {
            if (curg >= 0) {
                atomicAdd(&sums[curg * HID + f0 + 0], acc.x);
                atomicAdd(&sums[curg * HID + f0 + 1], acc.y);
                atomicAdd(&sums[curg * HID + f0 + 2], acc.z);
                atomicAdd(&sums[curg * HID + f0 + 3], acc.w);
            }
            acc = make_float4(0.f, 0.f, 0.f, 0.f);
            curg = g;
        }
        size_t base = (size_t)(c0 + li) * HID + f0;
        ushort4 hh = *(const ushort4*)(Hhi + base);
        ushort4 hl = *(const ushort4*)(Hlo + base);
        acc.x += h2f(hh.x) + h2f(hl.x);
        acc.y += h2f(hh.y) + h2f(hl.y);
        acc.z += h2f(hh.z) + h2f(hl.z);
        acc.w += h2f(hh.w) + h2f(hl.w);
    }
    if (curg >= 0) {
        atomicAdd(&sums[curg * HID + f0 + 0], acc.x);
        atomicAdd(&sums[curg * HID + f0 + 1], acc.y);
        atomicAdd(&sums[curg * HID + f0 + 2], acc.z);
        atomicAdd(&sums[curg * HID + f0 + 3], acc.w);
    }
}

__global__ __launch_bounds__(128) void pool_final(const float* __restrict__ sums,
                                                  const int* __restrict__ batch,
                                                  float* __restrict__ out, int N) {
    int g = blockIdx.x;
    int f = threadIdx.x;
    int lo = 0, hi = N;
    while (lo < hi) { int mid = (lo + hi) >> 1; if (batch[mid] < g) lo = mid + 1; else hi = mid; }
    int s0 = lo;
    lo = 0; hi = N;
    while (lo < hi) { int mid = (lo + hi) >> 1; if (batch[mid] < g + 1) lo = mid + 1; else hi = mid; }
    int cnt = lo - s0; if (cnt < 1) cnt = 1;
    out[g * HID + f] = sums[g * HID + f] / (float)cnt;
}

// ---------------- launch ----------------

extern "C" void kernel_launch(void* const* d_in, const int* in_sizes, int n_in,
                              void* d_out, int out_size, void* d_ws, size_t ws_size,
                              hipStream_t stream) {
    const float* x      = (const float*)d_in[0];
    const int*   ei     = (const int*)d_in[1];
    const int*   batch  = (const int*)d_in[2];
    const float* emb_W  = (const float*)d_in[3];
    const float* emb_b  = (const float*)d_in[4];
    const float* linlW  = (const float*)d_in[5];
    const float* linlb  = (const float*)d_in[6];
    const float* linrW  = (const float*)d_in[7];
    const float* linrb  = (const float*)d_in[8];
    const float* att    = (const float*)d_in[9];
    const float* convb  = (const float*)d_in[10];
    const float* lng    = (const float*)d_in[11];
    const float* lnb    = (const float*)d_in[12];
    float* out = (float*)d_out;

    const int N = in_sizes[0] / HID;     // 50000
    const int E = in_sizes[1] / 2;       // 800000
    const int NG = out_size / HID;       // 64
    const int NBK = (N + BKT_DSTS - 1) / BKT_DSTS;

    char* p = (char*)d_ws;
    unsigned short* xlh = (unsigned short*)p; p += (size_t)N * HID * 2;
    unsigned short* xrh = (unsigned short*)p; p += (size_t)N * HID * 2;
    unsigned short* hhi = (unsigned short*)p; p += (size_t)N * HID * 2;   // fp16 hi
    unsigned short* hlo = (unsigned short*)p; p += (size_t)N * HID * 2;   // fp16 lo
    unsigned short* wfrag = (unsigned short*)p; p += (32768 + 6 * 16384) * 2;
    // sums and deg adjacent -> single memset zeroes both
    float* sums       = (float*)p; p += (size_t)NG * HID * 4;
    int* deg          = (int*)p; p += (size_t)N * 4;
    int* offsets      = (int*)p; p += (size_t)N * 4;
    int* cur          = (int*)p; p += (size_t)N * 4;
    unsigned short* srt = (unsigned short*)p; p += ((size_t)NBK << CAP_SHIFT) * 2;

    size_t zbytes = (size_t)NG * HID * 4 + (size_t)N * 4;   // sums + deg
    hipMemsetAsync(sums, 0, zbytes, stream);

    // K1: degree count (1024 blocks) U prep_wfrag (448 blocks)
    k1_count_prep<<<CNT_BLOCKS + 448, 256, 0, stream>>>(ei, deg, E,
                                                        emb_W, linlW, linrW, wfrag);

    // K2: per-bucket scan (NBK blocks, hides) U fused emb+dual0 (gblk blocks)
    int gblk = (N + 63) / 64;
    k2_scan_embdual<<<gblk + NBK, 256, 0, stream>>>(deg, offsets, cur, N, gblk,
                                                    x, wfrag, emb_b, linlb, linrb,
                                                    hhi, hlo, xlh, xrh);

    // K3: scatter edges directly into srt (padded-bucket absolute positions)
    k3_scatter<<<SCT_BLOCKS, 256, 0, stream>>>(ei, cur, srt, E);

    // layer 0: gat (xl/xr from K2, CSR from K3)
    gat_layer<<<(N + 3) / 4, 256, 0, stream>>>(xlh, xrh, offsets, deg, srt,
                                               att, convb, lng, lnb, hhi, hlo, N);

    for (int l = 1; l < 3; ++l) {
        const unsigned short* wl = wfrag + 32768 + (size_t)(2 * l) * 16384;
        const unsigned short* wr = wfrag + 32768 + (size_t)(2 * l + 1) * 16384;
        gemm_dual_f16<<<gblk, 256, 0, stream>>>(hhi, wl, wr,
                                                linlb + (size_t)l * HID,
                                                linrb + (size_t)l * HID,
                                                xlh, xrh, N);
        gat_layer<<<(N + 3) / 4, 256, 0, stream>>>(xlh, xrh, offsets, deg, srt,
                                                   att + (size_t)l * HID,
                                                   convb + (size_t)l * HID,
                                                   lng + (size_t)l * HID,
                                                   lnb + (size_t)l * HID,
                                                   hhi, hlo, N);
    }

    pool_partial<<<(N + 63) / 64, 256, 0, stream>>>(hhi, hlo, batch, sums, N);
    pool_final<<<NG, 128, 0, stream>>>(sums, batch, out, N);
}

// Round 12
// 336.559 us; speedup vs baseline: 1.1830x; 1.1830x over previous
//
#include <hip/hip_runtime.h>
#include <hip/hip_bf16.h>
#include <math.h>

// GATv2 GNN: 3 layers, HIDDEN=128, HEADS=4, HEAD_DIM=32, + residual/ELU/LN, mean-pool.
//  - R22 (resubmit; R11 bench was an infra container failure — this exact
//    kernel == R18, already measured 337.96us in round 3, best known).
//    Session A/B ledger: R18=338.0 | R20 bin@1024=+14 | R19 pool-fuse=+73 |
//    R21 dense-CSR=+60. All deviations regressed -> hold measured optimum.
//  - R21 lesson: dense-CSR k3_scatter = 50us, WRITE_SIZE 42.7MB for 1.6MB
//    payload (26x write-allocate amplification: per-edge atomic slot
//    allocation interleaves 2B stores across 1024 blocks -> line thrash).
//    Scatter builds need write-LINE locality — reserve contiguous
//    per-(block,bucket) chunks (bin_edges' bulk cursor add).
//  - R20 lesson: same-address global atomic RMWs serialize at owning L2 slice;
//    contended-addr count is the cost (bin@1024: ~900 hits/addr = +14us).
//  - R19 lesson: per-block device-scope fences -> per-fence XCD-L2 writebacks
//    (8 non-coherent XCD L2s); last-block-done patterns fabric-serialize.
//  - R18: grid-stitch independent chains + fuse emb->dual0 (-9.7us vs 347.7).
//      K1 = bin_edges (256 blks) U prep_wfrag (448 blks)
//      K2 = fused emb+dual0 (782 blks) U bucket_build (391 blks)
//  - gat_layer pinned ~48.3us: random-gather service equilibrium (8 neutral
//    interventions). DO NOT TOUCH.
//  - R12 lesson: DPP row ops (0x140/0x141) illegal on gfx950.
//  - h stored as fp16 hi/lo pair; dual GEMM single-pass mfma f16 on hh (R14).
//  - CSR: padded-bucket 2-kernel build (R15). srt ushort. Pool: 2-stage (R1).

#define HID 128
#define BKT_SHIFT 7                 // 128 dsts per bucket
#define BKT_DSTS (1 << BKT_SHIFT)
#define CAP_SHIFT 12                // 4096 edge slots per bucket (avg ~2046)
#define CAP (1 << CAP_SHIFT)

typedef __attribute__((ext_vector_type(8))) short bf8_t;
typedef __attribute__((ext_vector_type(8))) _Float16 hf8_t;
typedef __attribute__((ext_vector_type(2))) _Float16 h2_t;
typedef __attribute__((ext_vector_type(4))) float f4_t;

__device__ __forceinline__ unsigned short f2bf(float f) {
    unsigned u = __float_as_uint(f);
    u += 0x7fff + ((u >> 16) & 1);          // RTNE
    return (unsigned short)(u >> 16);
}
__device__ __forceinline__ float bf2f(unsigned short h) {
    return __uint_as_float(((unsigned)h) << 16);
}
__device__ __forceinline__ unsigned short f2h(float f) {
    _Float16 h = (_Float16)f;               // RTNE
    return __builtin_bit_cast(unsigned short, h);
}
__device__ __forceinline__ float h2f(unsigned short u) {
    return (float)__builtin_bit_cast(_Float16, u);
}
__device__ __forceinline__ h2_t shfl_xor_h2(h2_t v, int m) {
    return __builtin_bit_cast(h2_t, __shfl_xor(__builtin_bit_cast(int, v), m, 64));
}

// ---------------- K1: bin_edges (blocks 0..255) U prep_wfrag (256..703) -------

__global__ __launch_bounds__(256) void k1_bin_prep(
    const int* __restrict__ ei, int* __restrict__ bucketCursor,
    int* __restrict__ tmp, int E, int NBK, int perBlk,
    const float* __restrict__ embW, const float* __restrict__ linlW,
    const float* __restrict__ linrW, unsigned short* __restrict__ frag) {
    __shared__ int hist[512];
    __shared__ int base[512];
    int tid = threadIdx.x;

    if (blockIdx.x < 256) {
        // ----- bin_edges: bulk per-(block,bucket) reservation -> dense writes
        int e0 = blockIdx.x * perBlk;
        int e1 = e0 + perBlk; if (e1 > E) e1 = E;

        for (int b = tid; b < NBK; b += 256) hist[b] = 0;
        __syncthreads();
        for (int e = e0 + tid; e < e1; e += 256)
            atomicAdd(&hist[ei[E + e] >> BKT_SHIFT], 1);
        __syncthreads();
        for (int b = tid; b < NBK; b += 256) {
            int c = hist[b];
            if (c > 0) base[b] = atomicAdd(&bucketCursor[b], c);
            hist[b] = 0;
        }
        __syncthreads();
        for (int e = e0 + tid; e < e1; e += 256) {
            int d = ei[E + e];
            int b = d >> BKT_SHIFT;
            int pos = (b << CAP_SHIFT) + base[b] + atomicAdd(&hist[b], 1);
            tmp[pos] = ei[e] | ((d & (BKT_DSTS - 1)) << 16);
        }
    } else {
        // ----- prep_wfrag: slot0 emb bf16 hi|lo; slots 1..6 fp16 single -----
        int bid = blockIdx.x - 256;           // 0..447
        int w = bid >> 6;                     // 0..6
        const float* W;
        if (w == 0)      W = embW;
        else if (w <= 3) W = linlW + (size_t)(w - 1) * 16384;
        else             W = linrW + (size_t)(w - 4) * 16384;

        int i = ((bid & 63) << 8) + tid;      // 0..16383
        int j = i & 7;
        int lane = (i >> 3) & 63;
        int t = i >> 9;                       // kk*8+nn
        int kk = t >> 3, nn = t & 7;
        int k = kk * 32 + (lane >> 4) * 8 + j;
        int n = nn * 16 + (lane & 15);
        float v = W[k * 128 + n];
        if (w == 0) {
            unsigned short hi = f2bf(v);
            frag[i] = hi;
            frag[16384 + i] = f2bf(v - bf2f(hi));
        } else {
            int slot = (w <= 3) ? (1 + 2 * (w - 1)) : (2 + 2 * (w - 4));
            frag[32768 + (size_t)(slot - 1) * 16384 + i] = f2h(v);
        }
    }
}

// ---------------- K2: fused emb->dual0 (blocks 0..GBLK-1) U bucket_build ------

__global__ __launch_bounds__(256) void k2_bucket_embdual(
    const int* __restrict__ tmp, const int* __restrict__ bucketCursor,
    int* __restrict__ offsets, int* __restrict__ deg,
    unsigned short* __restrict__ srt, int N, int GBLK,
    const float* __restrict__ Afp, const unsigned short* __restrict__ wfrag,
    const float* __restrict__ emb_b,
    const float* __restrict__ bl0, const float* __restrict__ br0,
    unsigned short* __restrict__ Chi, unsigned short* __restrict__ Clo,
    unsigned short* __restrict__ xl, unsigned short* __restrict__ xr) {
    __shared__ __align__(16) unsigned short As[2][64][136];
    int tid = threadIdx.x;

    if (blockIdx.x >= GBLK) {
        // ----- bucket_build (overlay hist/cur on As) -----
        int* hist = (int*)As;
        int* cur  = hist + BKT_DSTS;
        int b = blockIdx.x - GBLK;
        int d0 = b << BKT_SHIFT;
        if (tid < BKT_DSTS) hist[tid] = 0;
        __syncthreads();
        int start = b << CAP_SHIFT;
        int end = start + bucketCursor[b];
        for (int i = start + tid; i < end; i += 256)
            atomicAdd(&hist[(tmp[i] >> 16) & (BKT_DSTS - 1)], 1);
        __syncthreads();
        int v = (tid < BKT_DSTS) ? hist[tid] : 0;
        if (tid < BKT_DSTS) cur[tid] = v;
        __syncthreads();
        for (int off = 1; off < BKT_DSTS; off <<= 1) {
            int u = (tid < BKT_DSTS && tid >= off) ? cur[tid - off] : 0;
            __syncthreads();
            if (tid < BKT_DSTS) cur[tid] += u;
            __syncthreads();
        }
        if (tid < BKT_DSTS) {
            int ex = start + cur[tid] - v;     // exclusive prefix, absolute
            int d = d0 + tid;
            if (d < N) { offsets[d] = ex; deg[d] = v; }
            cur[tid] = ex;
        }
        __syncthreads();
        for (int i = start + tid; i < end; i += 256) {
            int r = tmp[i];
            int pos = atomicAdd(&cur[(r >> 16) & (BKT_DSTS - 1)], 1);
            srt[pos] = (unsigned short)(r & 0xFFFF);
        }
        return;
    }

    // ----- fused emb + dual0 -----
    int m0 = blockIdx.x * 64;

    #pragma unroll
    for (int i = 0; i < 8; ++i) {
        int idx = tid + i * 256;
        int r = idx >> 5, c4 = idx & 31;
        int row = m0 + r;
        float4 v = make_float4(0.f, 0.f, 0.f, 0.f);
        if (row < N) v = *(const float4*)(Afp + (size_t)row * HID + c4 * 4);
        ushort4 hi, lo;
        hi.x = f2bf(v.x); lo.x = f2bf(v.x - bf2f(hi.x));
        hi.y = f2bf(v.y); lo.y = f2bf(v.y - bf2f(hi.y));
        hi.z = f2bf(v.z); lo.z = f2bf(v.z - bf2f(hi.z));
        hi.w = f2bf(v.w); lo.w = f2bf(v.w - bf2f(hi.w));
        *(ushort4*)&As[0][r][c4 * 4] = hi;
        *(ushort4*)&As[1][r][c4 * 4] = lo;
    }
    __syncthreads();

    int wave = tid >> 6, lane = tid & 63;
    int mrow = lane & 15;
    int quad = lane >> 4;

    f4_t acc[8];
    #pragma unroll
    for (int nn = 0; nn < 8; ++nn) acc[nn] = (f4_t)(0.f);

    #pragma unroll
    for (int kk = 0; kk < 4; ++kk) {
        bf8_t ah = *(const bf8_t*)&As[0][wave * 16 + mrow][kk * 32 + quad * 8];
        bf8_t al = *(const bf8_t*)&As[1][wave * 16 + mrow][kk * 32 + quad * 8];
        const unsigned short* bp = wfrag + kk * 4096 + lane * 8;
        #pragma unroll
        for (int nn = 0; nn < 8; ++nn) {
            bf8_t bh = *(const bf8_t*)(bp + nn * 512);
            bf8_t bl = *(const bf8_t*)(bp + nn * 512 + 16384);
            acc[nn] = __builtin_amdgcn_mfma_f32_16x16x32_bf16(ah, bh, acc[nn], 0, 0, 0);
            acc[nn] = __builtin_amdgcn_mfma_f32_16x16x32_bf16(ah, bl, acc[nn], 0, 0, 0);
            acc[nn] = __builtin_amdgcn_mfma_f32_16x16x32_bf16(al, bh, acc[nn], 0, 0, 0);
        }
    }

    int lrow0 = wave * 16 + quad * 4;
    __syncthreads();   // all As bf16 reads done; stage h hi->plane0, lo->plane1
    #pragma unroll
    for (int nn = 0; nn < 8; ++nn) {
        int col = nn * 16 + mrow;
        float b = emb_b[col];
        #pragma unroll
        for (int r = 0; r < 4; ++r) {
            float o = acc[nn][r] + b;
            unsigned short hh = f2h(o);
            As[0][lrow0 + r][col] = hh;
            As[1][lrow0 + r][col] = f2h(o - h2f(hh));
        }
    }
    __syncthreads();

    // store h (hi/lo) AND pull dual0 A-fragments from the same staged tile
    hf8_t afr[4];
    #pragma unroll
    for (int kk = 0; kk < 4; ++kk)
        afr[kk] = *(const hf8_t*)&As[0][wave * 16 + mrow][kk * 32 + quad * 8];
    #pragma unroll
    for (int i = 0; i < 4; ++i) {
        int idx = tid + i * 256;
        int r = idx >> 4, c8 = idx & 15;
        int row = m0 + r;
        if (row < N) {
            *(uint4*)(Chi + (size_t)row * HID + c8 * 8) = *(uint4*)&As[0][r][c8 * 8];
            *(uint4*)(Clo + (size_t)row * HID + c8 * 8) = *(uint4*)&As[1][r][c8 * 8];
        }
    }

    // dual0 GEMM on in-register fragments (B = wfrag slots 1,2)
    f4_t acc0[8], acc1[8];
    #pragma unroll
    for (int nn = 0; nn < 8; ++nn) {
        acc0[nn] = (f4_t)(0.f);
        acc1[nn] = (f4_t)(0.f);
    }
    const unsigned short* Bl = wfrag + 32768;
    const unsigned short* Br = wfrag + 49152;
    #pragma unroll
    for (int kk = 0; kk < 4; ++kk) {
        const unsigned short* bp0 = Bl + kk * 4096 + lane * 8;
        const unsigned short* bp1 = Br + kk * 4096 + lane * 8;
        #pragma unroll
        for (int nn = 0; nn < 8; ++nn) {
            hf8_t bb0 = *(const hf8_t*)(bp0 + nn * 512);
            hf8_t bb1 = *(const hf8_t*)(bp1 + nn * 512);
            acc0[nn] = __builtin_amdgcn_mfma_f32_16x16x32_f16(afr[kk], bb0, acc0[nn], 0, 0, 0);
            acc1[nn] = __builtin_amdgcn_mfma_f32_16x16x32_f16(afr[kk], bb1, acc1[nn], 0, 0, 0);
        }
    }

    __syncthreads();   // h stores + frag reads done; restage xl->0, xr->1
    #pragma unroll
    for (int nn = 0; nn < 8; ++nn) {
        int col = nn * 16 + mrow;
        float bb0 = bl0[col];
        float bb1 = br0[col];
        #pragma unroll
        for (int r = 0; r < 4; ++r) {
            As[0][lrow0 + r][col] = f2h(acc0[nn][r] + bb0);
            As[1][lrow0 + r][col] = f2h(acc1[nn][r] + bb1);
        }
    }
    __syncthreads();
    #pragma unroll
    for (int i = 0; i < 4; ++i) {
        int idx = tid + i * 256;
        int r = idx >> 4, c8 = idx & 15;
        int row = m0 + r;
        if (row < N) {
            *(uint4*)(xl + (size_t)row * HID + c8 * 8) = *(uint4*)&As[0][r][c8 * 8];
            *(uint4*)(xr + (size_t)row * HID + c8 * 8) = *(uint4*)&As[1][r][c8 * 8];
        }
    }
}

// ---------------- dual GEMM (fp16 single-pass): xl/xr = h @ Wl/Wr + b ----------

__global__ __launch_bounds__(256) void gemm_dual_f16(
    const unsigned short* __restrict__ Ah,
    const unsigned short* __restrict__ Bf0, const unsigned short* __restrict__ Bf1,
    const float* __restrict__ b0, const float* __restrict__ b1,
    unsigned short* __restrict__ C0h, unsigned short* __restrict__ C1h, int M) {
    __shared__ __align__(16) unsigned short As[2][64][136];
    int m0 = blockIdx.x * 64;
    int tid = threadIdx.x;

    #pragma unroll
    for (int i = 0; i < 4; ++i) {
        int idx = tid + i * 256;
        int r = idx >> 4, c8 = idx & 15;
        int row = m0 + r;
        uint4 v = make_uint4(0, 0, 0, 0);
        if (row < M) v = *(const uint4*)(Ah + (size_t)row * HID + c8 * 8);
        *(uint4*)&As[0][r][c8 * 8] = v;
    }
    __syncthreads();

    int wave = tid >> 6, lane = tid & 63;
    int mrow = lane & 15;
    int quad = lane >> 4;

    f4_t acc0[8], acc1[8];
    #pragma unroll
    for (int nn = 0; nn < 8; ++nn) {
        acc0[nn] = (f4_t)(0.f);
        acc1[nn] = (f4_t)(0.f);
    }

    #pragma unroll
    for (int kk = 0; kk < 4; ++kk) {
        hf8_t a = *(const hf8_t*)&As[0][wave * 16 + mrow][kk * 32 + quad * 8];
        const unsigned short* bp0 = Bf0 + kk * 4096 + lane * 8;
        const unsigned short* bp1 = Bf1 + kk * 4096 + lane * 8;
        #pragma unroll
        for (int nn = 0; nn < 8; ++nn) {
            hf8_t bb0 = *(const hf8_t*)(bp0 + nn * 512);
            hf8_t bb1 = *(const hf8_t*)(bp1 + nn * 512);
            acc0[nn] = __builtin_amdgcn_mfma_f32_16x16x32_f16(a, bb0, acc0[nn], 0, 0, 0);
            acc1[nn] = __builtin_amdgcn_mfma_f32_16x16x32_f16(a, bb1, acc1[nn], 0, 0, 0);
        }
    }

    int lrow0 = wave * 16 + quad * 4;
    __syncthreads();   // all As reads done; stage xl->plane0, xr->plane1
    #pragma unroll
    for (int nn = 0; nn < 8; ++nn) {
        int col = nn * 16 + mrow;
        float bb0 = b0[col];
        float bb1 = b1[col];
        #pragma unroll
        for (int r = 0; r < 4; ++r) {
            As[0][lrow0 + r][col] = f2h(acc0[nn][r] + bb0);
            As[1][lrow0 + r][col] = f2h(acc1[nn][r] + bb1);
        }
    }
    __syncthreads();
    #pragma unroll
    for (int i = 0; i < 4; ++i) {
        int idx = tid + i * 256;
        int r = idx >> 4, c8 = idx & 15;
        int row = m0 + r;
        if (row < M) {
            *(uint4*)(C0h + (size_t)row * HID + c8 * 8) = *(uint4*)&As[0][r][c8 * 8];
            *(uint4*)(C1h + (size_t)row * HID + c8 * 8) = *(uint4*)&As[1][r][c8 * 8];
        }
    }
}

// ---------------- GATv2 layer (unchanged — pinned at gather equilibrium) -------

__device__ __forceinline__ void edge_math(uint4 rv, const h2_t xr2[4], const h2_t av2[4],
                                          h2_t xv[4], float* pOut) {
    const h2_t slope2 = {(_Float16)0.2f, (_Float16)0.2f};
    xv[0] = __builtin_bit_cast(h2_t, rv.x); xv[1] = __builtin_bit_cast(h2_t, rv.y);
    xv[2] = __builtin_bit_cast(h2_t, rv.z); xv[3] = __builtin_bit_cast(h2_t, rv.w);
    h2_t p2 = (h2_t)((_Float16)0.f);
    #pragma unroll
    for (int i = 0; i < 4; ++i) {
        h2_t e = xv[i] + xr2[i];
        e = __builtin_elementwise_max(e, e * slope2);
        p2 = e * av2[i] + p2;
    }
    *pOut = (float)p2[0] + (float)p2[1];
}

__global__ __launch_bounds__(256) void gat_layer(
    const unsigned short* __restrict__ xlh,   // fp16 [N,128]
    const unsigned short* __restrict__ xrh,   // fp16 [N,128]
    const int* __restrict__ offsets, const int* __restrict__ deg,
    const unsigned short* __restrict__ srt,
    const float* __restrict__ att,
    const float* __restrict__ convb,
    const float* __restrict__ lng, const float* __restrict__ lnb,
    unsigned short* __restrict__ Hhi, unsigned short* __restrict__ Hlo, int N) {
    int wv = (blockIdx.x * blockDim.x + threadIdx.x) >> 6;
    int lane = threadIdx.x & 63;
    if (wv >= N) return;
    int n = wv;
    int quarter = lane >> 4;
    int f0 = (lane & 15) * 8;
    const unsigned short* xbase = xlh + f0;

    h2_t xr2[4], av2[4];
    {
        uint4 xv = *(const uint4*)(xrh + (size_t)n * HID + f0);
        xr2[0] = __builtin_bit_cast(h2_t, xv.x);
        xr2[1] = __builtin_bit_cast(h2_t, xv.y);
        xr2[2] = __builtin_bit_cast(h2_t, xv.z);
        xr2[3] = __builtin_bit_cast(h2_t, xv.w);
        float a[8];
        *(float4*)&a[0] = *(const float4*)(att + f0);
        *(float4*)&a[4] = *(const float4*)(att + f0 + 4);
        #pragma unroll
        for (int i = 0; i < 4; ++i)
            av2[i] = (h2_t){(_Float16)a[2 * i], (_Float16)a[2 * i + 1]};
    }

    float d = 0.f;
    h2_t acc2[4];
    #pragma unroll
    for (int i = 0; i < 4; ++i) acc2[i] = (h2_t)((_Float16)0.f);
    int start = offsets[n], cnt = deg[n];

    int j = 0;
    for (; j + 16 <= cnt; j += 16) {
        int s[4];
        #pragma unroll
        for (int u = 0; u < 4; ++u) s[u] = srt[start + j + 4 * u + quarter];
        uint4 rv[4];
        #pragma unroll
        for (int u = 0; u < 4; ++u)
            rv[u] = *(const uint4*)(xbase + (size_t)s[u] * HID);
        h2_t xv[4][4];
        float p[4];
        #pragma unroll
        for (int u = 0; u < 4; ++u) edge_math(rv[u], xr2, av2, xv[u], &p[u]);
        h2_t p01 = {(_Float16)p[0], (_Float16)p[1]};
        h2_t p23 = {(_Float16)p[2], (_Float16)p[3]};
        p01 += shfl_xor_h2(p01, 1); p23 += shfl_xor_h2(p23, 1);
        p01 += shfl_xor_h2(p01, 2); p23 += shfl_xor_h2(p23, 2);
        float w[4];
        w[0] = __expf((float)p01[0]); w[1] = __expf((float)p01[1]);
        w[2] = __expf((float)p23[0]); w[3] = __expf((float)p23[1]);
        #pragma unroll
        for (int u = 0; u < 4; ++u) {
            d += w[u];
            h2_t w2 = (h2_t)((_Float16)w[u]);
            #pragma unroll
            for (int i = 0; i < 4; ++i) acc2[i] = w2 * xv[u][i] + acc2[i];
        }
    }
    for (; j + 4 <= cnt; j += 4) {
        int s = srt[start + j + quarter];
        uint4 rv = *(const uint4*)(xbase + (size_t)s * HID);
        h2_t xv[4];
        float p;
        edge_math(rv, xr2, av2, xv, &p);
        p += __shfl_xor(p, 1, 64);
        p += __shfl_xor(p, 2, 64);
        float w = __expf(p);
        d += w;
        h2_t w2 = (h2_t)((_Float16)w);
        #pragma unroll
        for (int i = 0; i < 4; ++i) acc2[i] = w2 * xv[i] + acc2[i];
    }
    if (j < cnt) {
        int r = cnt - j;
        int idx = j + quarter; if (idx > cnt - 1) idx = cnt - 1;
        int s = srt[start + idx];
        uint4 rv = *(const uint4*)(xbase + (size_t)s * HID);
        h2_t xv[4];
        float p;
        edge_math(rv, xr2, av2, xv, &p);
        p += __shfl_xor(p, 1, 64);
        p += __shfl_xor(p, 2, 64);
        float w = (quarter < r) ? __expf(p) : 0.f;
        d += w;
        h2_t w2 = (h2_t)((_Float16)w);
        #pragma unroll
        for (int i = 0; i < 4; ++i) acc2[i] = w2 * xv[i] + acc2[i];
    }

    #pragma unroll
    for (int i = 0; i < 4; ++i) {
        acc2[i] += shfl_xor_h2(acc2[i], 16);
        acc2[i] += shfl_xor_h2(acc2[i], 32);
    }
    d += __shfl_xor(d, 16, 64);
    d += __shfl_xor(d, 32, 64);

    float acc[8];
    #pragma unroll
    for (int i = 0; i < 4; ++i) {
        acc[2 * i]     = (float)acc2[i][0];
        acc[2 * i + 1] = (float)acc2[i][1];
    }

    float inv = 1.f / (d + 1e-16f);
    float t[8];
    {
        float cb[8];
        *(float4*)&cb[0] = *(const float4*)(convb + f0);
        *(float4*)&cb[4] = *(const float4*)(convb + f0 + 4);
        uint4 rh = *(const uint4*)(Hhi + (size_t)n * HID + f0);
        uint4 rl = *(const uint4*)(Hlo + (size_t)n * HID + f0);
        const unsigned short* hs = (const unsigned short*)&rh;
        const unsigned short* ls = (const unsigned short*)&rl;
        #pragma unroll
        for (int i = 0; i < 8; ++i) {
            float g = acc[i] * inv + cb[i];
            g = (g > 0.f) ? g : (__expf(g) - 1.f);
            t[i] = g + (h2f(hs[i]) + h2f(ls[i]));
        }
    }

    float sum = 0.f;
    #pragma unroll
    for (int i = 0; i < 8; ++i) sum += t[i];
    #pragma unroll
    for (int m = 1; m <= 8; m <<= 1) sum += __shfl_xor(sum, m, 64);
    float mu = sum * (1.f / 128.f);
    float q[8], vs = 0.f;
    #pragma unroll
    for (int i = 0; i < 8; ++i) { q[i] = t[i] - mu; vs += q[i] * q[i]; }
    #pragma unroll
    for (int m = 1; m <= 8; m <<= 1) vs += __shfl_xor(vs, m, 64);
    float rstd = rsqrtf(vs * (1.f / 128.f) + 1e-5f);

    if (quarter == 0) {
        float gv[8], bv[8], o[8];
        *(float4*)&gv[0] = *(const float4*)(lng + f0);
        *(float4*)&gv[4] = *(const float4*)(lng + f0 + 4);
        *(float4*)&bv[0] = *(const float4*)(lnb + f0);
        *(float4*)&bv[4] = *(const float4*)(lnb + f0 + 4);
        #pragma unroll
        for (int i = 0; i < 8; ++i) o[i] = q[i] * rstd * gv[i] + bv[i];
        unsigned short hh[8], hl[8];
        #pragma unroll
        for (int i = 0; i < 8; ++i) {
            hh[i] = f2h(o[i]);
            hl[i] = f2h(o[i] - h2f(hh[i]));
        }
        *(uint4*)(Hhi + (size_t)n * HID + f0) = *(uint4*)&hh[0];
        *(uint4*)(Hlo + (size_t)n * HID + f0) = *(uint4*)&hl[0];
    }
}

// ---------------- mean pool, 2-stage (reads fp16 hi/lo h) ----------------

__global__ __launch_bounds__(256) void pool_partial(const unsigned short* __restrict__ Hhi,
                                                    const unsigned short* __restrict__ Hlo,
                                                    const int* __restrict__ batch,
                                                    float* __restrict__ sums, int N) {
    __shared__ int bsh[64];
    int c0 = blockIdx.x * 64;
    int tid = threadIdx.x;
    if (tid < 64) bsh[tid] = (c0 + tid < N) ? batch[c0 + tid] : -1;
    __syncthreads();

    int r = tid >> 5;
    int f0 = (tid & 31) * 4;
    float4 acc = make_float4(0.f, 0.f, 0.f, 0.f);
    int curg = -1;
    #pragma unroll
    for (int i = 0; i < 8; ++i) {
        int li = r * 8 + i;
        int g = bsh[li];
        if (g < 0) break;
        if (g != curg) {
            if (curg >= 0) {
                atomicAdd(&sums[curg * HID + f0 + 0], acc.x);
                atomicAdd(&sums[curg * HID + f0 + 1], acc.y);
                atomicAdd(&sums[curg * HID + f0 + 2], acc.z);
                atomicAdd(&sums[curg * HID + f0 + 3], acc.w);
            }
            acc = make_float4(0.f, 0.f, 0.f, 0.f);
            curg = g;
        }
        size_t base = (size_t)(c0 + li) * HID + f0;
        ushort4 hh = *(const ushort4*)(Hhi + base);
        ushort4 hl = *(const ushort4*)(Hlo + base);
        acc.x += h2f(hh.x) + h2f(hl.x);
        acc.y += h2f(hh.y) + h2f(hl.y);
        acc.z += h2f(hh.z) + h2f(hl.z);
        acc.w += h2f(hh.w) + h2f(hl.w);
    }
    if (curg >= 0) {
        atomicAdd(&sums[curg * HID + f0 + 0], acc.x);
        atomicAdd(&sums[curg * HID + f0 + 1], acc.y);
        atomicAdd(&sums[curg * HID + f0 + 2], acc.z);
        atomicAdd(&sums[curg * HID + f0 + 3], acc.w);
    }
}

__global__ __launch_bounds__(128) void pool_final(const float* __restrict__ sums,
                                                  const int* __restrict__ batch,
                                                  float* __restrict__ out, int N) {
    int g = blockIdx.x;
    int f = threadIdx.x;
    int lo = 0, hi = N;
    while (lo < hi) { int mid = (lo + hi) >> 1; if (batch[mid] < g) lo = mid + 1; else hi = mid; }
    int s0 = lo;
    lo = 0; hi = N;
    while (lo < hi) { int mid = (lo + hi) >> 1; if (batch[mid] < g + 1) lo = mid + 1; else hi = mid; }
    int cnt = lo - s0; if (cnt < 1) cnt = 1;
    out[g * HID + f] = sums[g * HID + f] / (float)cnt;
}

// ---------------- launch ----------------

extern "C" void kernel_launch(void* const* d_in, const int* in_sizes, int n_in,
                              void* d_out, int out_size, void* d_ws, size_t ws_size,
                              hipStream_t stream) {
    const float* x      = (const float*)d_in[0];
    const int*   ei     = (const int*)d_in[1];
    const int*   batch  = (const int*)d_in[2];
    const float* emb_W  = (const float*)d_in[3];
    const float* emb_b  = (const float*)d_in[4];
    const float* linlW  = (const float*)d_in[5];
    const float* linlb  = (const float*)d_in[6];
    const float* linrW  = (const float*)d_in[7];
    const float* linrb  = (const float*)d_in[8];
    const float* att    = (const float*)d_in[9];
    const float* convb  = (const float*)d_in[10];
    const float* lng    = (const float*)d_in[11];
    const float* lnb    = (const float*)d_in[12];
    float* out = (float*)d_out;

    const int N = in_sizes[0] / HID;     // 50000
    const int E = in_sizes[1] / 2;       // 800000
    const int NG = out_size / HID;       // 64
    const int NBK = (N + BKT_DSTS - 1) / BKT_DSTS;

    char* p = (char*)d_ws;
    unsigned short* xlh = (unsigned short*)p; p += (size_t)N * HID * 2;
    unsigned short* xrh = (unsigned short*)p; p += (size_t)N * HID * 2;
    unsigned short* hhi = (unsigned short*)p; p += (size_t)N * HID * 2;   // fp16 hi
    unsigned short* hlo = (unsigned short*)p; p += (size_t)N * HID * 2;   // fp16 lo
    unsigned short* wfrag = (unsigned short*)p; p += (32768 + 6 * 16384) * 2;
    // sums and bucketCursor adjacent -> single memset zeroes both
    float* sums       = (float*)p; p += (size_t)NG * HID * 4;
    int* bucketCursor = (int*)p; p += (size_t)((NBK + 63) & ~63) * 4;
    int* deg          = (int*)p; p += (size_t)N * 4;
    int* offsets      = (int*)p; p += (size_t)N * 4;
    unsigned short* srt = (unsigned short*)p; p += ((size_t)NBK << CAP_SHIFT) * 2;
    int* tmp          = (int*)p; p += ((size_t)NBK << CAP_SHIFT) * 4;

    size_t zbytes = (size_t)NG * HID * 4 + (size_t)((NBK + 63) & ~63) * 4;
    hipMemsetAsync(sums, 0, zbytes, stream);

    // K1: bin_edges (256 blocks) U prep_wfrag (448 blocks) — independent chains
    int perBlk = (E + 255) / 256;
    k1_bin_prep<<<256 + 448, 256, 0, stream>>>(ei, bucketCursor, tmp, E, NBK, perBlk,
                                               emb_W, linlW, linrW, wfrag);

    // K2: fused emb+dual0 (gblk blocks) U bucket_build (NBK blocks)
    int gblk = (N + 63) / 64;
    k2_bucket_embdual<<<gblk + NBK, 256, 0, stream>>>(tmp, bucketCursor, offsets, deg,
                                                      srt, N, gblk,
                                                      x, wfrag, emb_b, linlb, linrb,
                                                      hhi, hlo, xlh, xrh);

    // layer 0: gat directly (xl/xr + CSR both produced by K2)
    gat_layer<<<(N + 3) / 4, 256, 0, stream>>>(xlh, xrh, offsets, deg, srt,
                                               att, convb, lng, lnb, hhi, hlo, N);

    for (int l = 1; l < 3; ++l) {
        const unsigned short* wl = wfrag + 32768 + (size_t)(2 * l) * 16384;
        const unsigned short* wr = wfrag + 32768 + (size_t)(2 * l + 1) * 16384;
        gemm_dual_f16<<<gblk, 256, 0, stream>>>(hhi, wl, wr,
                                                linlb + (size_t)l * HID,
                                                linrb + (size_t)l * HID,
                                                xlh, xrh, N);
        gat_layer<<<(N + 3) / 4, 256, 0, stream>>>(xlh, xrh, offsets, deg, srt,
                                                   att + (size_t)l * HID,
                                                   convb + (size_t)l * HID,
                                                   lng + (size_t)l * HID,
                                                   lnb + (size_t)l * HID,
                                                   hhi, hlo, N);
    }

    pool_partial<<<(N + 63) / 64, 256, 0, stream>>>(hhi, hlo, batch, sums, N);
    pool_final<<<NG, 128, 0, stream>>>(sums, batch, out, N);
}